// Round 2
// baseline (718.128 us; speedup 1.0000x reference)
//
#include <hip/hip_runtime.h>

typedef __attribute__((ext_vector_type(8))) short sv8;   // 8 bf16 (4 VGPRs) MFMA A/B frag
typedef __attribute__((ext_vector_type(4))) float fv4;   // 4 fp32 MFMA C/D frag

#define DEVI __device__ __forceinline__

static constexpr int T_ = 200;
static constexpr int F_ = 36;
static constexpr int WK = 96;        // padded K per layer GEMM
static constexpr int SA = 104;       // A-buffer k-stride in ushorts (bank-friendly: 2-way max)
static constexpr int A1_OFF = 0;                   // [16][SA]   L1 input (x | pad | h1 hi/lo | pad)
static constexpr int A2_OFF = 16 * SA;             // [2][16][SA] L2 input (h1 hi/lo | h2 hi/lo)
static constexpr int A3_OFF = A2_OFF + 2 * 16 * SA;// [2][16][SA] L3 input (h2 hi/lo | h3 hi/lo)
static constexpr int A_TOTAL = A3_OFF + 2 * 16 * SA; // 8320 ushorts, fits inside weight pool

DEVI float bf2f(unsigned short u) {
    union { unsigned int i; float f; } x; x.i = ((unsigned int)u) << 16; return x.f;
}
DEVI unsigned short f2bf(float f) {  // round-to-nearest-even fp32 -> bf16
    union { float f; unsigned int i; } x; x.f = f;
    unsigned int u = x.i;
    return (unsigned short)((u + 0x7fffu + ((u >> 16) & 1u)) >> 16);
}
DEVI float fsig(float x)  { return 1.0f / (1.0f + __expf(-x)); }          // inf-safe: ->0/1
DEVI float ftanh(float x) { float e = __expf(2.0f * x); return 1.0f - 2.0f / (e + 1.0f); } // ->-1/1

// ---------------- fused 3-layer LSTM + collapsed linear head ----------------
// 256 blocks x 256 threads; block owns 16 batch rows; 4 waves = layer pipeline stages.
__global__ __launch_bounds__(256, 1) void lstm_fused(
    const float* __restrict__ xg,
    const float* __restrict__ Wih1, const float* __restrict__ Whh1,
    const float* __restrict__ bih1, const float* __restrict__ bhh1,
    const float* __restrict__ Wih2, const float* __restrict__ Whh2,
    const float* __restrict__ bih2, const float* __restrict__ bhh2,
    const float* __restrict__ Wih3, const float* __restrict__ Whh3,
    const float* __restrict__ bih3, const float* __restrict__ bhh3,
    const float* __restrict__ W_fc1, const float* __restrict__ b_fc1,
    const float* __restrict__ W_fc2, const float* __restrict__ b_fc2,
    const float* __restrict__ W_cls, const float* __restrict__ b_cls,
    float* __restrict__ outp)
{
    // pool: first weights Wa[4][64][96] (bf16), then A-buffers carved into it
    __shared__ __align__(16) unsigned short pool[4 * 64 * WK];  // 49152 B
    __shared__ float biasS[256];
    __shared__ float T2s[512];   // [32][16] = W_fc2 @ W_fc1
    __shared__ float t2vs[32];   // b_fc2 + W_fc2 @ b_fc1
    __shared__ float Msh[96];    // [16][6] collapsed head matrix
    __shared__ float vsh[6];     // collapsed head bias

    const int tid  = threadIdx.x;
    const int wid  = tid >> 6;       // 0=L1, 1/2=L2 halves, 3=L3
    const int lane = tid & 63;
    const int nl   = lane & 15;
    const int quad = lane >> 4;
    const int b0   = blockIdx.x * 16;

    // ---- stage weights (fp32 -> bf16) as B^T layout Wa[w][n=gate*16+unit][k]; h-parts k-duplicated for hi/lo ----
    for (int idx = tid; idx < 4 * 64 * WK; idx += 256) {
        int w = idx / (64 * WK);
        int r = idx - w * (64 * WK);
        int n = r / WK;
        int k = r - n * WK;
        int g = n >> 4, u = n & 15;
        float v = 0.f;
        if (w == 0) {               // L1: [x(36) | 0(12) | h1 hi/lo(32) | 0(16)]
            int row = g * 16 + u;
            if (k < 36) v = Wih1[row * 36 + k];
            else if (k >= 48 && k < 80) v = Whh1[row * 16 + ((k - 48) >> 1)];
        } else if (w <= 2) {        // L2 half: [h1 hi/lo(32) | h2 hi/lo(64)]
            int row = g * 32 + (w - 1) * 16 + u;
            if (k < 32) v = Wih2[row * 16 + (k >> 1)];
            else        v = Whh2[row * 32 + ((k - 32) >> 1)];
        } else {                    // L3: [h2 hi/lo(64) | h3 hi/lo(32)]
            int row = g * 16 + u;
            if (k < 64) v = Wih3[row * 32 + (k >> 1)];
            else        v = Whh3[row * 16 + ((k - 64) >> 1)];
        }
        pool[idx] = f2bf(v);
    }
    // head: T2 = W_fc2 @ W_fc1 (fp32, global reads; 24KB total -> L1-resident)
    for (int idx = tid; idx < 512; idx += 256) {
        int b = idx >> 4, u = idx & 15;
        float acc = 0.f;
        for (int a = 0; a < 128; ++a) acc += W_fc2[b * 128 + a] * W_fc1[a * 16 + u];
        T2s[idx] = acc;
    }
    if (tid < 32) {
        float acc = b_fc2[tid];
        for (int a = 0; a < 128; ++a) acc += W_fc2[tid * 128 + a] * b_fc1[a];
        t2vs[tid] = acc;
    }
    {   // combined bias bih+bhh per gate row (fp32)
        int g = lane >> 4, u = lane & 15;
        int row; const float *bi, *bh;
        if (wid == 0)      { row = g * 16 + u;                  bi = bih1; bh = bhh1; }
        else if (wid <= 2) { row = g * 32 + (wid - 1) * 16 + u; bi = bih2; bh = bhh2; }
        else               { row = g * 16 + u;                  bi = bih3; bh = bhh3; }
        biasS[tid] = bi[row] + bh[row];
    }
    __syncthreads();

    // ---- register-resident B-frags: lane holds B[k=quad*8+j][n=lane&15] per 16x16 tile ----
    sv8 Bf[3][4];
    #pragma unroll
    for (int kt = 0; kt < 3; ++kt)
        #pragma unroll
        for (int nt = 0; nt < 4; ++nt)
            Bf[kt][nt] = *(const sv8*)&pool[wid * 64 * WK + (nt * 16 + nl) * WK + kt * 32 + quad * 8];
    float bias_r[4];
    #pragma unroll
    for (int nt = 0; nt < 4; ++nt) bias_r[nt] = biasS[wid * 64 + nt * 16 + nl];
    // collapsed head: M[u][j] = sum_b Wc[j][b]*T2[b][u];  v[j] = bc[j] + sum_b Wc[j][b]*t2v[b]
    if (tid < 96) {
        int u = tid / 6, j = tid - (tid / 6) * 6;
        float acc = 0.f;
        for (int b = 0; b < 32; ++b) acc += W_cls[j * 32 + b] * T2s[b * 16 + u];
        Msh[u * 6 + j] = acc;
    }
    if (tid < 6) {
        float acc = b_cls[tid];
        for (int b = 0; b < 32; ++b) acc += W_cls[tid * 32 + b] * t2vs[b];
        vsh[tid] = acc;
    }
    __syncthreads();   // all waves done reading pool weights; pool is reusable

    // ---- zero A-buffers (h(-1)=c(-1)=0, pads=0), then stage x(0) as bf16 ----
    for (int idx = tid; idx < A_TOTAL; idx += 256) pool[idx] = 0;
    __syncthreads();
    {
        const float2* xw2 = (const float2*)xg;
        for (int idx = tid; idx < 288; idx += 256) {   // 16 rows * 18 float2 (36 floats)
            int row = idx / 18, p = idx - (idx / 18) * 18;
            float2 xv = xw2[((b0 + row) * T_ + 0) * 18 + p];
            unsigned int pk = (unsigned int)f2bf(xv.x) | ((unsigned int)f2bf(xv.y) << 16);
            *(unsigned int*)&pool[A1_OFF + row * SA + 2 * p] = pk;
        }
    }
    __syncthreads();

    float c_st[4] = {0.f, 0.f, 0.f, 0.f};  // fp32 cell state: 4 batch-rows x 1 unit per lane

    for (int s = 0; s < T_ + 2; ++s) {
        const int rd = (s - 1) & 1, wr = s & 1;
        bool act;
        if (wid == 0)      act = (s < T_);                 // L1 at t=s
        else if (wid <= 2) act = (s >= 1 && s <= T_);      // L2 at t=s-1
        else               act = (s >= 2);                 // L3 at t=s-2
        if (act) {
            int abase;
            if (wid == 0)      abase = A1_OFF;
            else if (wid <= 2) abase = A2_OFF + rd * 16 * SA;
            else               abase = A3_OFF + rd * 16 * SA;
            sv8 Af[3];   // A[m=lane&15][k=quad*8+j]
            #pragma unroll
            for (int kt = 0; kt < 3; ++kt)
                Af[kt] = *(const sv8*)&pool[abase + nl * SA + kt * 32 + quad * 8];
            fv4 C[4];
            #pragma unroll
            for (int nt = 0; nt < 4; ++nt) { float b = bias_r[nt]; C[nt] = (fv4){b, b, b, b}; }
            #pragma unroll
            for (int kt = 0; kt < 3; ++kt)
                #pragma unroll
                for (int nt = 0; nt < 4; ++nt)
                    C[nt] = __builtin_amdgcn_mfma_f32_16x16x32_bf16(Af[kt], Bf[kt][nt], C[nt], 0, 0, 0);
            // C[nt][r] = gate nt (i,f,g,o), batch-row quad*4+r, unit nl
            #pragma unroll
            for (int r = 0; r < 4; ++r) {
                int m = quad * 4 + r;
                float gi = fsig(C[0][r]);
                float gf = fsig(C[1][r]);
                float gg = ftanh(C[2][r]);
                float go = fsig(C[3][r]);
                float c  = gf * c_st[r] + gi * gg;
                c_st[r] = c;
                float h  = go * ftanh(c);
                unsigned short hi = f2bf(h);
                unsigned short lo = f2bf(h - bf2f(hi));   // residual keeps recurrence ~fp32
                unsigned int pk = (unsigned int)hi | ((unsigned int)lo << 16);
                if (wid == 0) {
                    *(unsigned int*)&pool[A1_OFF + m * SA + 48 + 2 * nl] = pk;                  // own recurrence
                    *(unsigned int*)&pool[A2_OFF + wr * 16 * SA + m * SA + 2 * nl] = pk;        // feed L2
                } else if (wid <= 2) {
                    int ug = (wid - 1) * 16 + nl;
                    *(unsigned int*)&pool[A2_OFF + wr * 16 * SA + m * SA + 32 + 2 * ug] = pk;   // own recurrence
                    *(unsigned int*)&pool[A3_OFF + wr * 16 * SA + m * SA + 2 * ug] = pk;        // feed L3
                } else {
                    *(unsigned int*)&pool[A3_OFF + wr * 16 * SA + m * SA + 64 + 2 * nl] = pk;   // own recurrence
                }
            }
            // wave0 prefetches x(s+1) (fp32->bf16) after its frag reads; per-wave DS ops are in-order
            if (wid == 0 && s + 1 < T_) {
                const float2* xw2 = (const float2*)xg;
                #pragma unroll
                for (int i = 0; i < 5; ++i) {
                    int idx = i * 64 + lane;
                    if (idx < 288) {
                        int row = idx / 18, p = idx - (idx / 18) * 18;
                        float2 xv = xw2[((b0 + row) * T_ + (s + 1)) * 18 + p];
                        unsigned int pk = (unsigned int)f2bf(xv.x) | ((unsigned int)f2bf(xv.y) << 16);
                        *(unsigned int*)&pool[A1_OFF + row * SA + 2 * p] = pk;
                    }
                }
            }
        }
        __syncthreads();
    }

    // ---- epilogue: out[b][j] = h3(T-1) . M[:,j] + v[j]  (fp32 out) ----
    if (tid < 96) {
        int row = tid / 6, j = tid - (tid / 6) * 6;
        float acc = vsh[j];
        const int hb = A3_OFF + ((T_ + 1) & 1) * 16 * SA + row * SA + 64;
        #pragma unroll
        for (int u = 0; u < 16; ++u) {
            float h = bf2f(pool[hb + 2 * u]) + bf2f(pool[hb + 2 * u + 1]);
            acc += h * Msh[u * 6 + j];
        }
        outp[(b0 + row) * 6 + j] = acc;
    }
}

extern "C" void kernel_launch(void* const* d_in, const int* in_sizes, int n_in,
                              void* d_out, int out_size, void* d_ws, size_t ws_size,
                              hipStream_t stream) {
    const float* x     = (const float*)d_in[0];
    const float* Wih1  = (const float*)d_in[1];
    const float* Whh1  = (const float*)d_in[2];
    const float* bih1  = (const float*)d_in[3];
    const float* bhh1  = (const float*)d_in[4];
    const float* Wih2  = (const float*)d_in[5];
    const float* Whh2  = (const float*)d_in[6];
    const float* bih2  = (const float*)d_in[7];
    const float* bhh2  = (const float*)d_in[8];
    const float* Wih3  = (const float*)d_in[9];
    const float* Whh3  = (const float*)d_in[10];
    const float* bih3  = (const float*)d_in[11];
    const float* bhh3  = (const float*)d_in[12];
    const float* W_fc1 = (const float*)d_in[13];
    const float* b_fc1 = (const float*)d_in[14];
    const float* W_fc2 = (const float*)d_in[15];
    const float* b_fc2 = (const float*)d_in[16];
    const float* W_cls = (const float*)d_in[17];
    const float* b_cls = (const float*)d_in[18];

    lstm_fused<<<256, 256, 0, stream>>>(x,
        Wih1, Whh1, bih1, bhh1,
        Wih2, Whh2, bih2, bhh2,
        Wih3, Whh3, bih3, bhh3,
        W_fc1, b_fc1, W_fc2, b_fc2, W_cls, b_cls,
        (float*)d_out);
}

// Round 3
// 489.347 us; speedup vs baseline: 1.4675x; 1.4675x over previous
//
#include <hip/hip_runtime.h>

typedef __attribute__((ext_vector_type(8))) short sv8;   // 8 bf16 (4 VGPRs) MFMA A/B frag
typedef __attribute__((ext_vector_type(4))) float fv4;   // 4 fp32 MFMA C/D frag

#define DEVI __device__ __forceinline__

static constexpr int T_ = 200;
static constexpr int ROWS = 8;       // batch rows per block (512 blocks, 2 blocks/CU)
static constexpr int WK = 96;        // padded K per layer GEMM
static constexpr int SA = 104;       // A-buffer k-stride in ushorts (2-way bank alias max = free)
static constexpr int A1_OFF = 0;                   // [16][SA]   L1 input (x | pad | h1 hi/lo | pad)
static constexpr int A2_OFF = 16 * SA;             // [2][16][SA] L2 input (h1 hi/lo | h2 hi/lo)
static constexpr int A3_OFF = A2_OFF + 2 * 16 * SA;// [2][16][SA] L3 input (h2 hi/lo | h3 hi/lo)
static constexpr int A_TOTAL = A3_OFF + 2 * 16 * SA; // 8320 ushorts inside weight pool

DEVI float bf2f(unsigned short u) {
    union { unsigned int i; float f; } x; x.i = ((unsigned int)u) << 16; return x.f;
}
DEVI unsigned short f2bf(float f) {  // round-to-nearest-even fp32 -> bf16
    union { float f; unsigned int i; } x; x.f = f;
    unsigned int u = x.i;
    return (unsigned short)((u + 0x7fffu + ((u >> 16) & 1u)) >> 16);
}
#if __has_builtin(__builtin_amdgcn_rcpf)
DEVI float frcp(float x) { return __builtin_amdgcn_rcpf(x); }
#else
DEVI float frcp(float x) { return 1.0f / x; }
#endif
DEVI float fsig(float x)  { return frcp(1.0f + __expf(-x)); }                       // inf-safe -> 0/1
DEVI float ftanh(float x) { float e = __expf(2.0f * x); return 1.0f - 2.0f * frcp(e + 1.0f); } // -> -1/1

// ---------------- fused 3-layer LSTM + collapsed linear head ----------------
// 512 blocks x 256 threads; block owns 8 batch rows; 4 waves = layer pipeline stages.
__global__ __launch_bounds__(256, 2) void lstm_fused(
    const float* __restrict__ xg,
    const float* __restrict__ Wih1, const float* __restrict__ Whh1,
    const float* __restrict__ bih1, const float* __restrict__ bhh1,
    const float* __restrict__ Wih2, const float* __restrict__ Whh2,
    const float* __restrict__ bih2, const float* __restrict__ bhh2,
    const float* __restrict__ Wih3, const float* __restrict__ Whh3,
    const float* __restrict__ bih3, const float* __restrict__ bhh3,
    const float* __restrict__ W_fc1, const float* __restrict__ b_fc1,
    const float* __restrict__ W_fc2, const float* __restrict__ b_fc2,
    const float* __restrict__ W_cls, const float* __restrict__ b_cls,
    float* __restrict__ outp)
{
    // pool: first weights Wa[4][64][96] (bf16), then A-buffers carved into it
    __shared__ __align__(16) unsigned short pool[4 * 64 * WK];  // 49152 B
    __shared__ unsigned int xst[2 * 16 * ROWS * 18];            // x chunks, bf16x2-packed: [par][t&15][row][18]
    __shared__ float biasS[256];
    __shared__ float T2s[512];   // [32][16] = W_fc2 @ W_fc1
    __shared__ float t2vs[32];   // b_fc2 + W_fc2 @ b_fc1
    __shared__ float Msh[96];    // [16][6] collapsed head matrix
    __shared__ float vsh[6];     // collapsed head bias

    const int tid  = threadIdx.x;
    const int wid  = tid >> 6;       // 0=L1, 1/2=L2 halves, 3=L3
    const int lane = tid & 63;
    const int nl   = lane & 15;
    const int quad = lane >> 4;
    const int b0   = blockIdx.x * ROWS;

    // ---- stage weights (fp32 -> bf16) as B^T layout Wa[w][n=gate*16+unit][k]; h-parts k-duplicated for hi/lo ----
    for (int idx = tid; idx < 4 * 64 * WK; idx += 256) {
        int w = idx / (64 * WK);
        int r = idx - w * (64 * WK);
        int n = r / WK;
        int k = r - n * WK;
        int g = n >> 4, u = n & 15;
        float v = 0.f;
        if (w == 0) {               // L1: [x(36) | 0(12) | h1 hi/lo(32) | 0(16)]
            int row = g * 16 + u;
            if (k < 36) v = Wih1[row * 36 + k];
            else if (k >= 48 && k < 80) v = Whh1[row * 16 + ((k - 48) >> 1)];
        } else if (w <= 2) {        // L2 half: [h1 hi/lo(32) | h2 hi/lo(64)]
            int row = g * 32 + (w - 1) * 16 + u;
            if (k < 32) v = Wih2[row * 16 + (k >> 1)];
            else        v = Whh2[row * 32 + ((k - 32) >> 1)];
        } else {                    // L3: [h2 hi/lo(64) | h3 hi/lo(32)]
            int row = g * 16 + u;
            if (k < 64) v = Wih3[row * 32 + (k >> 1)];
            else        v = Whh3[row * 16 + ((k - 64) >> 1)];
        }
        pool[idx] = f2bf(v);
    }
    // head: T2 = W_fc2 @ W_fc1 (fp32; 24KB of weights -> L1/L2-resident)
    for (int idx = tid; idx < 512; idx += 256) {
        int b = idx >> 4, u = idx & 15;
        float acc = 0.f;
        for (int a = 0; a < 128; ++a) acc += W_fc2[b * 128 + a] * W_fc1[a * 16 + u];
        T2s[idx] = acc;
    }
    if (tid < 32) {
        float acc = b_fc2[tid];
        for (int a = 0; a < 128; ++a) acc += W_fc2[tid * 128 + a] * b_fc1[a];
        t2vs[tid] = acc;
    }
    {   // combined bias bih+bhh per gate row (fp32)
        int g = lane >> 4, u = lane & 15;
        int row; const float *bi, *bh;
        if (wid == 0)      { row = g * 16 + u;                  bi = bih1; bh = bhh1; }
        else if (wid <= 2) { row = g * 32 + (wid - 1) * 16 + u; bi = bih2; bh = bhh2; }
        else               { row = g * 16 + u;                  bi = bih3; bh = bhh3; }
        biasS[tid] = bi[row] + bh[row];
    }
    __syncthreads();

    // ---- register-resident B-frags: lane holds B[k=quad*8+j][n=lane&15] per 16x16 tile ----
    sv8 Bf[3][4];
    #pragma unroll
    for (int kt = 0; kt < 3; ++kt)
        #pragma unroll
        for (int nt = 0; nt < 4; ++nt)
            Bf[kt][nt] = *(const sv8*)&pool[wid * 64 * WK + (nt * 16 + nl) * WK + kt * 32 + quad * 8];
    float bias_r[4];
    #pragma unroll
    for (int nt = 0; nt < 4; ++nt) bias_r[nt] = biasS[wid * 64 + nt * 16 + nl];
    // collapsed head: M[u][j] = sum_b Wc[j][b]*T2[b][u];  v[j] = bc[j] + sum_b Wc[j][b]*t2v[b]
    if (tid < 96) {
        int u = tid / 6, j = tid - (tid / 6) * 6;
        float acc = 0.f;
        for (int b = 0; b < 32; ++b) acc += W_cls[j * 32 + b] * T2s[b * 16 + u];
        Msh[u * 6 + j] = acc;
    }
    if (tid < 6) {
        float acc = b_cls[tid];
        for (int b = 0; b < 32; ++b) acc += W_cls[tid * 32 + b] * t2vs[b];
        vsh[tid] = acc;
    }
    __syncthreads();   // all waves done reading pool weights; pool is reusable

    // ---- zero A-buffers (h(-1)=c(-1)=0, pads=0) + stage x chunk 0 into xst[0] ----
    for (int idx = tid; idx < A_TOTAL; idx += 256) pool[idx] = 0;
    {   // refill chunk 0
        const float2* xw2 = (const float2*)xg;
        #pragma unroll
        for (int i = 0; i < 9; ++i) {
            int j = tid + i * 256;                  // < 2304
            int row = j / 288, rem = j - row * 288;
            int tl = rem / 18, p = rem - tl * 18;
            float2 xv = xw2[((size_t)(b0 + row) * T_ + tl) * 18 + p];
            xst[(tl * ROWS + row) * 18 + p] = (unsigned int)f2bf(xv.x) | ((unsigned int)f2bf(xv.y) << 16);
        }
    }
    __syncthreads();
    // copy x(0) into A1 (u32 view: row stride SA/2 = 52)
    if (tid < ROWS * 18) {
        int row = tid / 18, p = tid - (tid / 18) * 18;
        ((unsigned int*)pool)[row * (SA / 2) + p] = xst[(0 * ROWS + row) * 18 + p];
    }
    __syncthreads();

    float c_st[4] = {0.f, 0.f, 0.f, 0.f};  // fp32 cell state: 4 batch-rows x 1 unit per lane

    for (int s = 0; s < T_ + 2; ++s) {
        const int rd = (s - 1) & 1, wr = s & 1;
        // chunk refill: at interval start, all threads stage chunk (s/16 + 1) into other parity.
        // Loads issue here, drain at this step's end barrier (hidden under ~3000cy of compute).
        if ((s & 15) == 0) {
            int cn = (s >> 4) + 1;
            if (cn <= 12) {
                const float2* xw2 = (const float2*)xg;
                unsigned int* dst = &xst[(cn & 1) * 16 * ROWS * 18];
                int tbase = cn * 16;
                #pragma unroll
                for (int i = 0; i < 9; ++i) {
                    int j = tid + i * 256;
                    int row = j / 288, rem = j - row * 288;
                    int tl = rem / 18, p = rem - tl * 18;
                    int t = tbase + tl;
                    if (t < T_) {
                        float2 xv = xw2[((size_t)(b0 + row) * T_ + t) * 18 + p];
                        dst[(tl * ROWS + row) * 18 + p] = (unsigned int)f2bf(xv.x) | ((unsigned int)f2bf(xv.y) << 16);
                    }
                }
            }
        }
        bool act;
        if (wid == 0)      act = (s < T_);                 // L1 at t=s
        else if (wid <= 2) act = (s >= 1 && s <= T_);      // L2 at t=s-1
        else               act = (s >= 2);                 // L3 at t=s-2
        if (act) {
            int abase;
            if (wid == 0)      abase = A1_OFF;
            else if (wid <= 2) abase = A2_OFF + rd * 16 * SA;
            else               abase = A3_OFF + rd * 16 * SA;
            sv8 Af[3];   // A[m=lane&15][k=quad*8+j]
            #pragma unroll
            for (int kt = 0; kt < 3; ++kt)
                Af[kt] = *(const sv8*)&pool[abase + nl * SA + kt * 32 + quad * 8];
            // wave0: copy x(s+1) xstage -> A1 (after own frag reads; per-wave LDS ops are in-order)
            if (wid == 0 && s + 1 < T_) {
                int t = s + 1;
                const unsigned int* src = &xst[((t >> 4) & 1) * 16 * ROWS * 18 + (t & 15) * ROWS * 18];
                unsigned int* dstA = (unsigned int*)pool;   // A1 u32 view
                #pragma unroll
                for (int i = 0; i < 3; ++i) {
                    int idx = i * 64 + lane;
                    if (idx < ROWS * 18) {
                        int row = idx / 18, p = idx - (idx / 18) * 18;
                        dstA[row * (SA / 2) + p] = src[idx];
                    }
                }
            }
            fv4 C[4];
            #pragma unroll
            for (int nt = 0; nt < 4; ++nt) { float b = bias_r[nt]; C[nt] = (fv4){b, b, b, b}; }
            #pragma unroll
            for (int kt = 0; kt < 3; ++kt)
                #pragma unroll
                for (int nt = 0; nt < 4; ++nt)
                    C[nt] = __builtin_amdgcn_mfma_f32_16x16x32_bf16(Af[kt], Bf[kt][nt], C[nt], 0, 0, 0);
            // C[nt][r] = gate nt (i,f,g,o), batch-row quad*4+r, unit nl
            #pragma unroll
            for (int r = 0; r < 4; ++r) {
                int m = quad * 4 + r;
                float gi = fsig(C[0][r]);
                float gf = fsig(C[1][r]);
                float gg = ftanh(C[2][r]);
                float go = fsig(C[3][r]);
                float c  = gf * c_st[r] + gi * gg;
                c_st[r] = c;
                float h  = go * ftanh(c);
                unsigned short hi = f2bf(h);
                unsigned short lo = f2bf(h - bf2f(hi));   // residual keeps recurrence ~fp32
                unsigned int pk = (unsigned int)hi | ((unsigned int)lo << 16);
                if (wid == 0) {
                    *(unsigned int*)&pool[A1_OFF + m * SA + 48 + 2 * nl] = pk;                  // own recurrence
                    *(unsigned int*)&pool[A2_OFF + wr * 16 * SA + m * SA + 2 * nl] = pk;        // feed L2
                } else if (wid <= 2) {
                    int ug = (wid - 1) * 16 + nl;
                    *(unsigned int*)&pool[A2_OFF + wr * 16 * SA + m * SA + 32 + 2 * ug] = pk;   // own recurrence
                    *(unsigned int*)&pool[A3_OFF + wr * 16 * SA + m * SA + 2 * ug] = pk;        // feed L3
                } else {
                    *(unsigned int*)&pool[A3_OFF + wr * 16 * SA + m * SA + 64 + 2 * nl] = pk;   // own recurrence
                }
            }
        }
        __syncthreads();
    }

    // ---- epilogue: out[b][j] = h3(T-1) . M[:,j] + v[j]  (fp32 out) ----
    if (tid < ROWS * 6) {
        int row = tid / 6, j = tid - (tid / 6) * 6;
        float acc = vsh[j];
        const int hb = A3_OFF + ((T_ + 1) & 1) * 16 * SA + row * SA + 64;
        #pragma unroll
        for (int u = 0; u < 16; ++u) {
            float h = bf2f(pool[hb + 2 * u]) + bf2f(pool[hb + 2 * u + 1]);
            acc += h * Msh[u * 6 + j];
        }
        outp[(b0 + row) * 6 + j] = acc;
    }
}

extern "C" void kernel_launch(void* const* d_in, const int* in_sizes, int n_in,
                              void* d_out, int out_size, void* d_ws, size_t ws_size,
                              hipStream_t stream) {
    const float* x     = (const float*)d_in[0];
    const float* Wih1  = (const float*)d_in[1];
    const float* Whh1  = (const float*)d_in[2];
    const float* bih1  = (const float*)d_in[3];
    const float* bhh1  = (const float*)d_in[4];
    const float* Wih2  = (const float*)d_in[5];
    const float* Whh2  = (const float*)d_in[6];
    const float* bih2  = (const float*)d_in[7];
    const float* bhh2  = (const float*)d_in[8];
    const float* Wih3  = (const float*)d_in[9];
    const float* Whh3  = (const float*)d_in[10];
    const float* bih3  = (const float*)d_in[11];
    const float* bhh3  = (const float*)d_in[12];
    const float* W_fc1 = (const float*)d_in[13];
    const float* b_fc1 = (const float*)d_in[14];
    const float* W_fc2 = (const float*)d_in[15];
    const float* b_fc2 = (const float*)d_in[16];
    const float* W_cls = (const float*)d_in[17];
    const float* b_cls = (const float*)d_in[18];

    lstm_fused<<<512, 256, 0, stream>>>(x,
        Wih1, Whh1, bih1, bhh1,
        Wih2, Whh2, bih2, bhh2,
        Wih3, Whh3, bih3, bhh3,
        W_fc1, b_fc1, W_fc2, b_fc2, W_cls, b_cls,
        (float*)d_out);
}